// Round 2
// baseline (768.735 us; speedup 1.0000x reference)
//
#include <hip/hip_runtime.h>

typedef float  floatx4 __attribute__((ext_vector_type(4)));
typedef short  shortx8 __attribute__((ext_vector_type(8)));

union Frag { shortx8 s; uint4 u4; };

#define LDW 72                       // Ws row stride (elements): 144B
#define CEXP 0.18033688011112042f    // 0.125 * log2(e)

__device__ __forceinline__ short f2bf(float f) {
  union { float f; unsigned u; } v; v.f = f;
  unsigned r = v.u + 0x7fffu + ((v.u >> 16) & 1u);   // RNE
  return (short)(r >> 16);
}

__device__ __forceinline__ unsigned cvt_pk_bf16(float a, float b) {
  unsigned r;
  asm("v_cvt_pk_bf16_f32 %0, %1, %2" : "=v"(r) : "v"(a), "v"(b));
  return r;
}

__device__ __forceinline__ float exp2_hw(float x) {   // D = 2^S0, single v_exp_f32
  float r;
  asm("v_exp_f32 %0, %1" : "=v"(r) : "v"(x));
  return r;
}

// async global->LDS, 16B per lane; LDS dest must be wave-uniform base (HW adds lane*16)
__device__ __forceinline__ void gl2lds(const void* g, void* l) {
  __builtin_amdgcn_global_load_lds(
      (const __attribute__((address_space(1))) unsigned int*)g,
      (__attribute__((address_space(3))) unsigned int*)l, 16, 0, 0);
}

// ---------------- x fp32 -> bf16 ----------------
__global__ __launch_bounds__(256) void k_convert_x(const float* __restrict__ x,
                                                   short* __restrict__ xb) {
  int i = (blockIdx.x * 256 + threadIdx.x) * 4;
  const float4 v = *(const float4*)(x + i);
  union { short s[4]; uint2 u; } o;
  o.s[0] = f2bf(v.x); o.s[1] = f2bf(v.y); o.s[2] = f2bf(v.z); o.s[3] = f2bf(v.w);
  *(uint2*)(xb + i) = o.u;
}

// ---------------- W[k][n] fp32 -> Wt[n][k] bf16 (once per call) ----------------
__global__ __launch_bounds__(256) void k_transpose(const float* __restrict__ W0,
    const float* __restrict__ W1, const float* __restrict__ W2,
    const float* __restrict__ W3, short* __restrict__ Wt) {
  __shared__ short tile[64][65];
  const float* W = blockIdx.z == 0 ? W0 : blockIdx.z == 1 ? W1 : blockIdx.z == 2 ? W2 : W3;
  short* T = Wt + (size_t)blockIdx.z * 1048576;
  int t = threadIdx.x;
  int k0 = blockIdx.x * 64, n0 = blockIdx.y * 64;
  #pragma unroll
  for (int i = 0; i < 16; i++) {
    int idx = i * 256 + t; int kr = idx >> 6, nc = idx & 63;
    tile[nc][kr] = f2bf(W[(size_t)(k0 + kr) * 1024 + n0 + nc]);
  }
  __syncthreads();
  #pragma unroll
  for (int i = 0; i < 16; i++) {
    int idx = i * 256 + t; int nr = idx >> 6, kc = idx & 63;
    T[(size_t)(n0 + nr) * 1024 + k0 + kc] = tile[nr][kc];
  }
}

// ---------------- shared GEMM core: 128x128 tile, K=1024, BK=64 ----------------
// m97 pattern: global_load_lds dwordx4 staging into linear LDS with an XOR swizzle
// applied on BOTH sides: element (row,c) lives at LDS[row*64 + (c ^ ((row&7)<<3))],
// achieved by inverse-swizzling the per-lane GLOBAL column: col = ((l&7)^(l>>3))*8
// (row&7 == l>>3 for this mapping); b128 fragment reads apply the same XOR.
__device__ __forceinline__ void gemm_core(const short* __restrict__ A,
    const short* __restrict__ Bt, int bm, int bn, short* As, short* Bs,
    floatx4 acc[4][4]) {
  int t = threadIdx.x;
  int lane = t & 63, g = lane >> 4, m = lane & 15;
  int wv = t >> 6, wm = wv >> 1, wn = wv & 1;
  int l3 = lane >> 3, l7 = lane & 7;
  int col = (l7 ^ l3) << 3;
  const short* Ag = A  + (size_t)(bm + wv * 8 + l3) * 1024 + col;
  const short* Bg = Bt + (size_t)(bn + wv * 8 + l3) * 1024 + col;
  short* Asl = As + wv * 512;     // wave-uniform LDS base
  short* Bsl = Bs + wv * 512;
  int sw = (m & 7) << 3;
  for (int kb = 0; kb < 16; kb++) {
    __syncthreads();               // prior frag reads done before overwrite
    #pragma unroll
    for (int it = 0; it < 4; it++) {
      gl2lds(Ag + (size_t)it * 32768 + kb * 64, Asl + it * 2048);
      gl2lds(Bg + (size_t)it * 32768 + kb * 64, Bsl + it * 2048);
    }
    __syncthreads();               // compiler drains vmcnt before barrier
    #pragma unroll
    for (int ks = 0; ks < 2; ks++) {
      int kox = (ks * 32 + g * 8) ^ sw;
      Frag af[4], bfr[4];
      #pragma unroll
      for (int mt = 0; mt < 4; mt++)
        af[mt].u4 = *(const uint4*)(As + (wm * 64 + mt * 16 + m) * 64 + kox);
      #pragma unroll
      for (int nt = 0; nt < 4; nt++)
        bfr[nt].u4 = *(const uint4*)(Bs + (wn * 64 + nt * 16 + m) * 64 + kox);
      #pragma unroll
      for (int mt = 0; mt < 4; mt++)
        #pragma unroll
        for (int nt = 0; nt < 4; nt++)
          acc[mt][nt] = __builtin_amdgcn_mfma_f32_16x16x32_bf16(af[mt].s, bfr[nt].s, acc[mt][nt], 0, 0, 0);
    }
  }
}

// ---------------- QKV projections (grid.z = 0/1/2) ----------------
__global__ __launch_bounds__(256) void k_proj_qkv(const short* __restrict__ xb,
    const short* __restrict__ Wt, const float* __restrict__ bq,
    const float* __restrict__ bk, const float* __restrict__ bv,
    short* __restrict__ qw, short* __restrict__ kw, short* __restrict__ vw) {
  __shared__ __align__(16) short As[128 * 64];
  __shared__ __align__(16) short Bs[128 * 64];
  int z = blockIdx.z;
  const short* Bt = Wt + (size_t)z * 1048576;
  const float* bias = z == 0 ? bq : z == 1 ? bk : bv;
  short* dst = z == 0 ? qw : z == 1 ? kw : vw;
  floatx4 acc[4][4];
  #pragma unroll
  for (int i = 0; i < 4; i++)
    #pragma unroll
    for (int j = 0; j < 4; j++) acc[i][j] = (floatx4){0.f, 0.f, 0.f, 0.f};
  int bm = blockIdx.x * 128, bn = blockIdx.y * 128;
  gemm_core(xb, Bt, bm, bn, As, Bs, acc);
  int t = threadIdx.x, lane = t & 63, g = lane >> 4, m = lane & 15;
  int wv = t >> 6, wm = wv >> 1, wn = wv & 1;
  #pragma unroll
  for (int nt = 0; nt < 4; nt++) {
    int col = bn + wn * 64 + nt * 16 + m;
    float bb = bias[col];
    int h = col >> 6, d = col & 63;
    #pragma unroll
    for (int mt = 0; mt < 4; mt++)
      #pragma unroll
      for (int r = 0; r < 4; r++) {
        int row = bm + wm * 64 + mt * 16 + g * 4 + r;
        float val = acc[mt][nt][r] + bb;
        int b_ = row >> 11, s_ = row & 2047;
        if (z == 2)
          dst[((size_t)((b_ * 16 + h) * 64 + d)) * 2048 + s_] = f2bf(val);
        else
          dst[((size_t)((b_ * 16 + h) * 2048 + s_)) * 64 + d] = f2bf(val);
      }
  }
}

// ---------------- output projection: out = O @ Wo + bo (fp32 store) ----------------
__global__ __launch_bounds__(256) void k_proj_out(const short* __restrict__ ow,
    const short* __restrict__ Wt, const float* __restrict__ bo,
    float* __restrict__ out) {
  __shared__ __align__(16) short As[128 * 64];
  __shared__ __align__(16) short Bs[128 * 64];
  floatx4 acc[4][4];
  #pragma unroll
  for (int i = 0; i < 4; i++)
    #pragma unroll
    for (int j = 0; j < 4; j++) acc[i][j] = (floatx4){0.f, 0.f, 0.f, 0.f};
  int bm = blockIdx.x * 128, bn = blockIdx.y * 128;
  gemm_core(ow, Wt, bm, bn, As, Bs, acc);
  int t = threadIdx.x, lane = t & 63, g = lane >> 4, m = lane & 15;
  int wv = t >> 6, wm = wv >> 1, wn = wv & 1;
  #pragma unroll
  for (int nt = 0; nt < 4; nt++) {
    int col = bn + wn * 64 + nt * 16 + m;
    float bb = bo[col];
    #pragma unroll
    for (int mt = 0; mt < 4; mt++)
      #pragma unroll
      for (int r = 0; r < 4; r++) {
        int row = bm + wm * 64 + mt * 16 + g * 4 + r;
        out[(size_t)row * 1024 + col] = acc[mt][nt][r] + bb;
      }
  }
}

// ---------------- swapped scores: S^T = K @ Q^T ----------------
// sacc[nt][mt]: lane holds query = mt*16 + (lane&15), keys = nt*16 + g*4 + r
// (4 CONSECUTIVE keys per lane -> float4 attn stores + packed bf16 writes).
__device__ __forceinline__ void score_swapped(const short* Qs, const short* Ks,
    int wv, int g, int m, floatx4 sacc[4][2]) {
  #pragma unroll
  for (int i = 0; i < 4; i++) {
    sacc[i][0] = (floatx4){0.f, 0.f, 0.f, 0.f};
    sacc[i][1] = (floatx4){0.f, 0.f, 0.f, 0.f};
  }
  int sw = (m & 7) << 3;
  #pragma unroll
  for (int ks = 0; ks < 2; ks++) {
    int kox = (ks * 32 + g * 8) ^ sw;
    Frag kf[4], qf[2];
    #pragma unroll
    for (int nt = 0; nt < 4; nt++)
      kf[nt].u4 = *(const uint4*)(Ks + (nt * 16 + m) * 64 + kox);
    #pragma unroll
    for (int mt = 0; mt < 2; mt++)
      qf[mt].u4 = *(const uint4*)(Qs + (wv * 32 + mt * 16 + m) * 64 + kox);
    #pragma unroll
    for (int nt = 0; nt < 4; nt++)
      #pragma unroll
      for (int mt = 0; mt < 2; mt++)
        sacc[nt][mt] = __builtin_amdgcn_mfma_f32_16x16x32_bf16(kf[nt].s, qf[mt].s, sacc[nt][mt], 0, 0, 0);
  }
}

// ---------------- attention: per (bh, 128-row q-tile), two-pass softmax ----------------
// Q,K [B*H, S, 64] bf16; Vt [B*H, 64, S] bf16; attn fp32 [B*H,S,S]; O bf16 [B*S,1024]
__global__ __launch_bounds__(256) void k_attn(const short* __restrict__ Q,
    const short* __restrict__ K, const short* __restrict__ Vt,
    float* __restrict__ attn, short* __restrict__ O) {
  __shared__ __align__(16) short Qs[128 * 64];   // swizzled (gload_lds)
  __shared__ __align__(16) short Ks[64 * 64];    // swizzled
  __shared__ __align__(16) short Vs[64 * 64];    // swizzled, rows = dk
  __shared__ __align__(16) short Ws[128 * LDW];  // P bf16, padded (VALU-written)
  int t = threadIdx.x;
  int lane = t & 63, g = lane >> 4, m = lane & 15, wv = t >> 6;
  int l3 = lane >> 3, l7 = lane & 7;
  int col = (l7 ^ l3) << 3;
  int qt = blockIdx.x, bh = blockIdx.y;

  const short* qsrc = Q  + ((size_t)bh * 2048 + qt * 128 + wv * 8 + l3) * 64 + col;
  const short* ksrc = K  + ((size_t)bh * 2048 + wv * 8 + l3) * 64 + col;
  const short* vsrc = Vt + ((size_t)bh * 64 + wv * 8 + l3) * 2048 + col;
  short* ql = Qs + wv * 512;
  short* kl = Ks + wv * 512;
  short* vl = Vs + wv * 512;

  #pragma unroll
  for (int it = 0; it < 4; it++)           // persistent Q tile
    gl2lds(qsrc + it * 2048, ql + it * 2048);

  // ---- pass A: per-lane partial row sums; cross-lane reduce ONCE at end ----
  float z0 = 0.f, z1 = 0.f;
  for (int kt = 0; kt < 32; kt++) {
    __syncthreads();
    gl2lds(ksrc + (size_t)kt * 4096,        kl);
    gl2lds(ksrc + (size_t)kt * 4096 + 2048, kl + 2048);
    __syncthreads();
    floatx4 s[4][2];
    score_swapped(Qs, Ks, wv, g, m, s);
    #pragma unroll
    for (int nt = 0; nt < 4; nt++) {
      z0 += exp2_hw(s[nt][0][0] * CEXP) + exp2_hw(s[nt][0][1] * CEXP)
          + exp2_hw(s[nt][0][2] * CEXP) + exp2_hw(s[nt][0][3] * CEXP);
      z1 += exp2_hw(s[nt][1][0] * CEXP) + exp2_hw(s[nt][1][1] * CEXP)
          + exp2_hw(s[nt][1][2] * CEXP) + exp2_hw(s[nt][1][3] * CEXP);
    }
  }
  z0 += __shfl_xor(z0, 16); z0 += __shfl_xor(z0, 32);
  z1 += __shfl_xor(z1, 16); z1 += __shfl_xor(z1, 32);
  float rz0 = 1.0f / z0, rz1 = 1.0f / z1;

  // ---- pass B: recompute scores, emit weights (float4 NT stores), PV ----
  floatx4 oacc[2][4];
  #pragma unroll
  for (int i = 0; i < 2; i++)
    #pragma unroll
    for (int j = 0; j < 4; j++) oacc[i][j] = (floatx4){0.f, 0.f, 0.f, 0.f};
  float* ab0 = attn + ((size_t)bh * 2048 + qt * 128 + wv * 32 + m) * 2048;
  float* ab1 = ab0 + (size_t)16 * 2048;
  short* wr0 = Ws + (wv * 32 + m) * LDW;
  short* wr1 = wr0 + 16 * LDW;
  int sw = (m & 7) << 3;
  for (int kt = 0; kt < 32; kt++) {
    __syncthreads();
    gl2lds(ksrc + (size_t)kt * 4096,        kl);
    gl2lds(ksrc + (size_t)kt * 4096 + 2048, kl + 2048);
    gl2lds(vsrc + (size_t)kt * 64,          vl);
    gl2lds(vsrc + (size_t)kt * 64 + 65536,  vl + 2048);
    __syncthreads();
    floatx4 s[4][2];
    score_swapped(Qs, Ks, wv, g, m, s);
    #pragma unroll
    for (int nt = 0; nt < 4; nt++) {
      floatx4 w0, w1;
      #pragma unroll
      for (int r = 0; r < 4; r++) {
        w0[r] = exp2_hw(s[nt][0][r] * CEXP) * rz0;
        w1[r] = exp2_hw(s[nt][1][r] * CEXP) * rz1;
      }
      __builtin_nontemporal_store(w0, (floatx4*)(ab0 + (size_t)kt * 64 + nt * 16 + g * 4));
      __builtin_nontemporal_store(w1, (floatx4*)(ab1 + (size_t)kt * 64 + nt * 16 + g * 4));
      *(uint2*)(wr0 + nt * 16 + g * 4) = make_uint2(cvt_pk_bf16(w0[0], w0[1]), cvt_pk_bf16(w0[2], w0[3]));
      *(uint2*)(wr1 + nt * 16 + g * 4) = make_uint2(cvt_pk_bf16(w1[0], w1[1]), cvt_pk_bf16(w1[2], w1[3]));
    }
    // PV: O += P @ V  (Ws write->read same-wave; compiler inserts lgkmcnt wait)
    #pragma unroll
    for (int ks = 0; ks < 2; ks++) {
      int ko = ks * 32 + g * 8;
      int kox = ko ^ sw;
      Frag pa[2], vb[4];
      pa[0].u4 = *(const uint4*)(Ws + (wv * 32 + m) * LDW + ko);
      pa[1].u4 = *(const uint4*)(Ws + (wv * 32 + 16 + m) * LDW + ko);
      #pragma unroll
      for (int dt = 0; dt < 4; dt++)
        vb[dt].u4 = *(const uint4*)(Vs + (dt * 16 + m) * 64 + kox);
      #pragma unroll
      for (int mt = 0; mt < 2; mt++)
        #pragma unroll
        for (int dt = 0; dt < 4; dt++)
          oacc[mt][dt] = __builtin_amdgcn_mfma_f32_16x16x32_bf16(pa[mt].s, vb[dt].s, oacc[mt][dt], 0, 0, 0);
    }
  }
  // O in token-major layout for the final projection GEMM
  int b_ = bh >> 4, h_ = bh & 15;
  #pragma unroll
  for (int mt = 0; mt < 2; mt++)
    #pragma unroll
    for (int dt = 0; dt < 4; dt++)
      #pragma unroll
      for (int r = 0; r < 4; r++) {
        int tok = qt * 128 + wv * 32 + mt * 16 + g * 4 + r;
        O[((size_t)(b_ * 2048 + tok)) * 1024 + h_ * 64 + dt * 16 + m] = f2bf(oacc[mt][dt][r]);
      }
}

extern "C" void kernel_launch(void* const* d_in, const int* in_sizes, int n_in,
                              void* d_out, int out_size, void* d_ws, size_t ws_size,
                              hipStream_t stream) {
  const float* x  = (const float*)d_in[0];
  const float* Wq = (const float*)d_in[1];
  const float* bq = (const float*)d_in[2];
  const float* Wk = (const float*)d_in[3];
  const float* bk = (const float*)d_in[4];
  const float* Wv = (const float*)d_in[5];
  const float* bv = (const float*)d_in[6];
  const float* Wo = (const float*)d_in[7];
  const float* bo = (const float*)d_in[8];

  char* ws = (char*)d_ws;
  short* xb = (short*)(ws);                 // 8 MB  x as bf16 [4096][1024]
  short* Wt = (short*)(ws + 8388608);       // 8 MB  4x Wt[n][k] bf16 (q,k,v,o)
  short* qw = (short*)(ws + 16777216);      // 8 MB  [B,H,S,dk]
  short* kw = (short*)(ws + 25165824);      // 8 MB  [B,H,S,dk]
  short* vw = (short*)(ws + 33554432);      // 8 MB  [B,H,dk,S]
  short* ow = (short*)(ws + 41943040);      // 8 MB  [B*S,1024]   (total 48 MB)

  float* out  = (float*)d_out;              // [2,2048,1024]
  float* attn = out + 4194304;              // [2,16,2048,2048]

  k_convert_x<<<4096, 256, 0, stream>>>(x, xb);
  k_transpose<<<dim3(16, 16, 4), 256, 0, stream>>>(Wq, Wk, Wv, Wo, Wt);
  k_proj_qkv<<<dim3(32, 8, 3), 256, 0, stream>>>(xb, Wt, bq, bk, bv, qw, kw, vw);
  k_attn<<<dim3(16, 32), 256, 0, stream>>>(qw, kw, vw, attn, ow);
  k_proj_out<<<dim3(32, 8), 256, 0, stream>>>(ow, Wt + 3145728, bo, out);
}